// Round 13
// baseline (161.090 us; speedup 1.0000x reference)
//
#include <hip/hip_runtime.h>
#include <hip/hip_bf16.h>

// PosteriorRotationN: B=8,T=120,N=24,D=48,C=1128,DE=256
// Single fused kernel per bn (grid 192, 1024 thr):
//   sp[t,c] = XW[t,:]·ctx[c,:] + spb[t],  XW = x·Wkv (bf16, LDS),  spb = x·bkv
//   g = 0.1*tanh(sp) -> sG chunk (double-buffered)
//   dx[t,e] = sum_{i>e} x[i]g(T(i)+e) - sum_{j<e} x[j]g(T(e)+j);  out = x + dx
// Producer waves (0-7): ctx loads + MFMA + g. Consumer waves (8-15): pair gather.
// ctx (222 MB) is read exactly once; kv is never materialized (k1 eliminated).

constexpr int Bc = 8, Tc = 120, Nc = 24, Dc = 48, Cc = 1128, DEc = 256;
constexpr int BNc = Bc * Nc;    // 192

using short8 = __attribute__((ext_vector_type(8))) short;
using f32x4  = __attribute__((ext_vector_type(4))) float;

__device__ __forceinline__ ushort f2b(float f) {
    union { float f; unsigned u; } v; v.f = f;
    unsigned r = (v.u + 0x7fffu + ((v.u >> 16) & 1u)) >> 16;
    return (ushort)r;
}
__device__ __forceinline__ float b2f(ushort u) {
    union { unsigned q; float f; } cv; cv.q = ((unsigned)u) << 16; return cv.f;
}
__device__ __forceinline__ short8 pack8(const float4& a, const float4& b) {
    short8 r;
    r[0] = (short)f2b(a.x); r[1] = (short)f2b(a.y); r[2] = (short)f2b(a.z); r[3] = (short)f2b(a.w);
    r[4] = (short)f2b(b.x); r[5] = (short)f2b(b.y); r[6] = (short)f2b(b.z); r[7] = (short)f2b(b.w);
    return r;
}

constexpr int WTs = 64;    // sWT stride (ushort): WkvT [e][d], d-pad 48..63 zero
constexpr int XFs = 52;    // sXf stride (f32); col 48 holds spb[t]
constexpr int XWs = 264;   // sXW stride (ushort), 16B-aligned rows
constexpr int GSs = 74;    // sG stride (ushort) per chunk row
constexpr int XBs = 72;    // sXb stride (ushort), aliased into sG[0]
constexpr int NCH = 18;    // 18 chunks x 64 c (71 c-frags incl. clamp-pad)

__global__ __launch_bounds__(1024, 4) void k2f(const float* __restrict__ x,
                                               const float* __restrict__ ctx,
                                               const float* __restrict__ Wkv,
                                               const float* __restrict__ bkv,
                                               float* __restrict__ out) {
    __shared__ ushort sWT[256 * WTs];     // 32768 B
    __shared__ float  sXf[Tc * XFs];      // 24960 B
    __shared__ ushort sXW[128 * XWs];     // 67584 B
    __shared__ ushort sG[2][128 * GSs];   // 37888 B  (total 163200 <= 160 KiB)
    ushort* sXb = &sG[0][0];              // alias, phase 0 only (needs 18432 B)

    const int bn = blockIdx.x, b = bn / Nc, n = bn % Nc;
    const int tid = threadIdx.x, wave = tid >> 6, lane = tid & 63;
    const int tr = lane & 15, kg = lane >> 4;
    const float* ctxb = ctx + ((size_t)b * Cc * Nc + n) * DEc;
    const float* xb   = x + ((size_t)b * Tc * Nc + n) * Dc;

    // ---- phase 0a: zero sXb; stage WkvT (bf16, [e][d], pad d 48-63 = 0) ----
    for (int l = tid; l < 128 * XBs / 8; l += 1024)
        *reinterpret_cast<short8*>(&sXb[l * 8]) = (short8){0, 0, 0, 0, 0, 0, 0, 0};
    {   // pad cols: 256 e x 16 d = 1024 ushort4
        int e = tid >> 2, q = tid & 3;
        *reinterpret_cast<ushort4*>(&sWT[e * WTs + 48 + q * 4]) = make_ushort4(0, 0, 0, 0);
    }
    for (int l = tid; l < Dc * DEc; l += 1024) {
        int d = l >> 8, e = l & 255;
        sWT[e * WTs + d] = f2b(Wkv[l]);
    }
    __syncthreads();
    // ---- phase 0b: stage x -> sXf (f32) + sXb (bf16, zero-padded) ----
    for (int l = tid; l < Tc * 12; l += 1024) {
        int t = l / 12, dv = (l % 12) * 4;
        float4 v = *reinterpret_cast<const float4*>(xb + (size_t)t * Nc * Dc + dv);
        *reinterpret_cast<float4*>(&sXf[t * XFs + dv]) = v;
        *reinterpret_cast<ushort4*>(&sXb[t * XBs + dv]) =
            make_ushort4(f2b(v.x), f2b(v.y), f2b(v.z), f2b(v.w));
    }
    __syncthreads();
    // ---- phase 0c: spb[t] = x[t]·bkv (into sXf col 48); XW = x·Wkv via MFMA ----
    if (tid < Tc) {
        float a = 0.f;
        for (int d = 0; d < Dc; ++d) a += sXf[tid * XFs + d] * bkv[d];
        sXf[tid * XFs + 48] = a;
    }
    {
        int m = wave & 7, nb = (wave >> 3) * 8;
        short8 a0 = *reinterpret_cast<const short8*>(&sXb[(m * 16 + tr) * XBs + kg * 8]);
        short8 a1 = *reinterpret_cast<const short8*>(&sXb[(m * 16 + tr) * XBs + 32 + kg * 8]);
        #pragma unroll
        for (int j = 0; j < 8; ++j) {
            int nf = nb + j;
            short8 b0 = *reinterpret_cast<const short8*>(&sWT[(nf * 16 + tr) * WTs + kg * 8]);
            short8 b1 = *reinterpret_cast<const short8*>(&sWT[(nf * 16 + tr) * WTs + 32 + kg * 8]);
            f32x4 acc = (f32x4){0.f, 0.f, 0.f, 0.f};
            acc = __builtin_amdgcn_mfma_f32_16x16x32_bf16(a0, b0, acc, 0, 0, 0);
            acc = __builtin_amdgcn_mfma_f32_16x16x32_bf16(a1, b1, acc, 0, 0, 0);
            #pragma unroll
            for (int r = 0; r < 4; ++r)      // D: col=e (tr), row=t (kg*4+r)
                sXW[(m * 16 + kg * 4 + r) * XWs + nf * 16 + tr] = f2b(acc[r]);
        }
    }
    __syncthreads();

    // ---- chunk loop: producers (waves 0-7) / consumers (waves 8-15) ----
    if (wave < 8) {
        const int mq = wave & 3, nq = wave >> 2;   // m-frags {mq,mq+4}; local n-frags {2nq,2nq+1}
        const ushort* arow0 = &sXW[(mq * 16 + tr) * XWs];
        const ushort* arow1 = &sXW[((mq + 4) * 16 + tr) * XWs];
        for (int ch = 0; ch < NCH + 1; ++ch) {
            if (ch < NCH) {
                int g0 = ch * 4 + 2 * nq, g1 = g0 + 1;
                int ca = g0 * 16 + tr; if (ca > Cc - 1) ca = Cc - 1;
                int cb = g1 * 16 + tr; if (cb > Cc - 1) cb = Cc - 1;
                const float* pa = ctxb + (size_t)ca * (Nc * DEc) + kg * 8;
                const float* pb = ctxb + (size_t)cb * (Nc * DEc) + kg * 8;
                f32x4 acc[2][2];
                #pragma unroll
                for (int mi = 0; mi < 2; ++mi)
                    #pragma unroll
                    for (int ni = 0; ni < 2; ++ni) acc[mi][ni] = (f32x4){0.f, 0.f, 0.f, 0.f};
                float4 fa0 = *reinterpret_cast<const float4*>(pa);
                float4 fa1 = *reinterpret_cast<const float4*>(pa + 4);
                float4 fb0 = *reinterpret_cast<const float4*>(pb);
                float4 fb1 = *reinterpret_cast<const float4*>(pb + 4);
                #pragma unroll
                for (int ks = 0; ks < 8; ++ks) {
                    float4 na0, na1, nb0, nb1;
                    if (ks < 7) {
                        na0 = *reinterpret_cast<const float4*>(pa + (ks + 1) * 32);
                        na1 = *reinterpret_cast<const float4*>(pa + (ks + 1) * 32 + 4);
                        nb0 = *reinterpret_cast<const float4*>(pb + (ks + 1) * 32);
                        nb1 = *reinterpret_cast<const float4*>(pb + (ks + 1) * 32 + 4);
                    }
                    short8 bf0 = pack8(fa0, fa1), bf1 = pack8(fb0, fb1);
                    short8 af0 = *reinterpret_cast<const short8*>(arow0 + ks * 32 + kg * 8);
                    short8 af1 = *reinterpret_cast<const short8*>(arow1 + ks * 32 + kg * 8);
                    acc[0][0] = __builtin_amdgcn_mfma_f32_16x16x32_bf16(af0, bf0, acc[0][0], 0, 0, 0);
                    acc[0][1] = __builtin_amdgcn_mfma_f32_16x16x32_bf16(af0, bf1, acc[0][1], 0, 0, 0);
                    acc[1][0] = __builtin_amdgcn_mfma_f32_16x16x32_bf16(af1, bf0, acc[1][0], 0, 0, 0);
                    acc[1][1] = __builtin_amdgcn_mfma_f32_16x16x32_bf16(af1, bf1, acc[1][1], 0, 0, 0);
                    fa0 = na0; fa1 = na1; fb0 = nb0; fb1 = nb1;
                }
                ushort* gb = &sG[ch & 1][0];
                int lc0 = 2 * nq * 16 + tr, lc1 = lc0 + 16;
                #pragma unroll
                for (int mi = 0; mi < 2; ++mi) {
                    int trow = (mq + mi * 4) * 16 + kg * 4;
                    #pragma unroll
                    for (int r = 0; r < 4; ++r) {
                        int ts = trow + r; if (ts > Tc - 1) ts = Tc - 1;
                        float sb = sXf[ts * XFs + 48];
                        float s0 = acc[mi][0][r] + sb, s1 = acc[mi][1][r] + sb;
                        float gv0 = 0.1f - 0.2f * __builtin_amdgcn_rcpf(__expf(2.f * s0) + 1.f);
                        float gv1 = 0.1f - 0.2f * __builtin_amdgcn_rcpf(__expf(2.f * s1) + 1.f);
                        gb[(trow + r) * GSs + lc0] = f2b(gv0);
                        gb[(trow + r) * GSs + lc1] = f2b(gv1);
                    }
                }
            }
            __syncthreads();
        }
    } else {
        const int ct = tid - 512;
        const int tB = ct >> 2, eg = ct & 3;
        const bool act = tB < Tc;
        const float* xrow = &sXf[tB * XFs];
        float dx[12]; int ii[12], Tv[12], Te[12];
        #pragma unroll
        for (int p = 0; p < 12; ++p) {
            int e = eg + 4 * p;
            Te[p] = e * (e - 1) / 2;
            ii[p] = e + 1;
            Tv[p] = (e + 1) * e / 2;
            dx[p] = 0.f;
        }
        for (int ch = 0; ch < NCH + 1; ++ch) {
            if (ch > 0 && act) {
                const int c0 = (ch - 1) * 64, c1 = c0 + 64;
                const ushort* grow = &sG[(ch - 1) & 1][tB * GSs];
                #pragma unroll
                for (int p = 0; p < 12; ++p) {
                    int e = eg + 4 * p;
                    // j-side: c = T(e)+j, j < e
                    int jlo = c0 - Te[p]; if (jlo < 0) jlo = 0;
                    int jhi = c1 - Te[p]; if (jhi > e) jhi = e;
                    for (int j = jlo; j < jhi; ++j)
                        dx[p] -= xrow[j] * b2f(grow[Te[p] + j - c0]);
                    // i-side: c = T(i)+e, i > e (monotone walk)
                    while (ii[p] < Dc && Tv[p] + e < c1) {
                        dx[p] += xrow[ii[p]] * b2f(grow[Tv[p] + e - c0]);
                        Tv[p] += ii[p]; ++ii[p];
                    }
                }
            }
            __syncthreads();
        }
        if (act) {
            float* orow = out + (((size_t)b * Tc + tB) * Nc + n) * Dc;
            #pragma unroll
            for (int p = 0; p < 12; ++p) {
                int e = eg + 4 * p;
                orow[e] = sXf[tB * XFs + e] + dx[p];
            }
        }
    }
}

extern "C" void kernel_launch(void* const* d_in, const int* in_sizes, int n_in,
                              void* d_out, int out_size, void* d_ws, size_t ws_size,
                              hipStream_t stream) {
    (void)in_sizes; (void)n_in; (void)out_size; (void)d_ws; (void)ws_size;
    const float* x   = (const float*)d_in[0];
    const float* ctx = (const float*)d_in[1];
    const float* Wkv = (const float*)d_in[2];
    const float* bkv = (const float*)d_in[3];
    float* out = (float*)d_out;

    k2f<<<dim3(BNc), dim3(1024), 0, stream>>>(x, ctx, Wkv, bkv, out);
}

// Round 14
// 94.769 us; speedup vs baseline: 1.6998x; 1.6998x over previous
//
#include <hip/hip_runtime.h>
#include <hip/hip_bf16.h>

// PosteriorRotationN: B=8,T=120,N=24,D=48,C=1128,DE=256
// k0w: Wkv f32 -> bf16 (24 KB, L2-resident)
// k1 : kv GEMM (bf16 MFMA, swapped operands, bn-grid) -> kvb[bn][c][64]   [97.6-µs config]
// k2 : TT=16; phase A sp MFMA (3-slot ring, 2-deep kv prefetch) -> g bf16 -> sG[t][c];
//      phase B R6-structure gather dot. LDS 39.8 KB -> 4 blocks/CU, 16 waves.

constexpr int Bc = 8, Tc = 120, Nc = 24, Dc = 48, Cc = 1128, DEc = 256;
constexpr int BNc = Bc * Nc;        // 192
constexpr int KVP = 64;             // kv row padded to 64 (zeros at 48..63)

using short8 = __attribute__((ext_vector_type(8))) short;
using f32x4  = __attribute__((ext_vector_type(4))) float;

__device__ __forceinline__ ushort f2b(float f) {
    union { float f; unsigned u; } v; v.f = f;
    unsigned r = (v.u + 0x7fffu + ((v.u >> 16) & 1u)) >> 16;
    return (ushort)r;
}
__device__ __forceinline__ float b2f(ushort u) {
    union { unsigned q; float f; } cv; cv.q = ((unsigned)u) << 16; return cv.f;
}
__device__ __forceinline__ short bcast(float f) {
    return (short)__bfloat16_as_ushort(__float2bfloat16(f));
}
__device__ __forceinline__ short8 pack8(const float4& a, const float4& b) {
    short8 r;
    r[0] = bcast(a.x); r[1] = bcast(a.y); r[2] = bcast(a.z); r[3] = bcast(a.w);
    r[4] = bcast(b.x); r[5] = bcast(b.y); r[6] = bcast(b.z); r[7] = bcast(b.w);
    return r;
}

// ---------------- K0w: Wkv f32 -> bf16 ----------------
__global__ void k0w(const float* __restrict__ Wkv, ushort* __restrict__ wkvb) {
    int i = blockIdx.x * 256 + threadIdx.x;
    float4 w = *reinterpret_cast<const float4*>(Wkv + i * 4);
    ushort4 u;
    u.x = (ushort)bcast(w.x); u.y = (ushort)bcast(w.y);
    u.z = (ushort)bcast(w.z); u.w = (ushort)bcast(w.w);
    *reinterpret_cast<ushort4*>(wkvb + i * 4) = u;
}

// ---------------- K1: kv GEMM, bf16 MFMA, swapped operands (97.6-µs config) ----------------
constexpr int SWs = 264;  // Wkv LDS stride (bf16 elems)
__global__ __launch_bounds__(256) void k1_kv(const float* __restrict__ ctx,
                                             const ushort* __restrict__ wkvb,
                                             const float* __restrict__ bkv,
                                             ushort* __restrict__ kvb) {
    __shared__ ushort sW[Dc * SWs];          // 25344 B
    const int bn = blockIdx.x, c0 = blockIdx.y * 128;
    const int b = bn / Nc, n = bn % Nc;
    const int tid = threadIdx.x, wave = tid >> 6, lane = tid & 63;
    const int tr = lane & 15, kg = lane >> 4;
    const float* ctxb = ctx + ((size_t)b * Cc * Nc + n) * DEc;

    for (int l = tid; l < Dc * 32; l += 256) {
        int d = l >> 5, e = (l & 31) << 3;
        *reinterpret_cast<short8*>(&sW[d * SWs + e]) =
            *reinterpret_cast<const short8*>(&wkvb[d * DEc + e]);
    }

    const float* crow[2];
    #pragma unroll
    for (int cn = 0; cn < 2; ++cn) {
        int c = c0 + wave * 32 + cn * 16 + tr;
        crow[cn] = ctxb + (size_t)(c < Cc ? c : Cc - 1) * (Nc * DEc);
    }

    f32x4 acc[3][2];
    #pragma unroll
    for (int mf = 0; mf < 3; ++mf)
        #pragma unroll
        for (int cn = 0; cn < 2; ++cn) acc[mf][cn] = (f32x4){0.f, 0.f, 0.f, 0.f};

    __syncthreads();

    #pragma unroll
    for (int ks = 0; ks < 8; ++ks) {
        const int e0 = ks * 32 + kg * 8;
        short8 bfrag[2];
        #pragma unroll
        for (int cn = 0; cn < 2; ++cn) {
            float4 a0 = *reinterpret_cast<const float4*>(crow[cn] + e0);
            float4 a1 = *reinterpret_cast<const float4*>(crow[cn] + e0 + 4);
            bfrag[cn] = pack8(a0, a1);
        }
        short8 afrag[3];
        #pragma unroll
        for (int mf = 0; mf < 3; ++mf)
            afrag[mf] = *reinterpret_cast<const short8*>(&sW[(mf * 16 + tr) * SWs + e0]);
        #pragma unroll
        for (int mf = 0; mf < 3; ++mf)
            #pragma unroll
            for (int cn = 0; cn < 2; ++cn)
                acc[mf][cn] = __builtin_amdgcn_mfma_f32_16x16x32_bf16(afrag[mf], bfrag[cn], acc[mf][cn], 0, 0, 0);
    }

    float4 bias[3];
    #pragma unroll
    for (int mf = 0; mf < 3; ++mf)
        bias[mf] = *reinterpret_cast<const float4*>(bkv + mf * 16 + kg * 4);
    #pragma unroll
    for (int cn = 0; cn < 2; ++cn) {
        int c = c0 + wave * 32 + cn * 16 + tr;
        if (c < Cc) {
            ushort* dst = kvb + ((size_t)bn * Cc + c) * KVP;
            #pragma unroll
            for (int mf = 0; mf < 3; ++mf) {
                ushort4 u;
                u.x = f2b(acc[mf][cn][0] + bias[mf].x);
                u.y = f2b(acc[mf][cn][1] + bias[mf].y);
                u.z = f2b(acc[mf][cn][2] + bias[mf].z);
                u.w = f2b(acc[mf][cn][3] + bias[mf].w);
                *reinterpret_cast<ushort4*>(dst + mf * 16 + kg * 4) = u;
            }
        }
    }
    {
        int row = lane >> 1, half = lane & 1;
        int c = c0 + wave * 32 + row;
        if (c < Cc) {
            short8 z = (short8){0, 0, 0, 0, 0, 0, 0, 0};
            *reinterpret_cast<short8*>(&kvb[((size_t)bn * Cc + c) * KVP + 48 + half * 8]) = z;
        }
    }
}

// ---------------- K2: TT=16, bf16 sG, ring-prefetch phase A, 4 blk/CU ----------------
// grid 1536 = 192 bn x 8 t-tiles(16), XCD-swizzled (L&7 == bn%8 matches k1's XCD).
constexpr int SG2 = 1140;  // ushort stride (2280 B)
__global__ __launch_bounds__(256, 4) void k2_fused(const float* __restrict__ x,
                                                   const ushort* __restrict__ kvb,
                                                   float* __restrict__ out) {
    __shared__ ushort sG[16 * SG2];    // 36480 B (bf16 g)
    __shared__ float  sXf[16 * 52];    // 3328 B  -> 39808 B total
    const int L = blockIdx.x;
    const int bn = (L & 7) + 8 * (L >> 6);   // bn%8 == XCD slot
    const int tt = (L >> 3) & 7;
    const int b = bn / Nc, n = bn % Nc, t0 = tt * 16;
    const int tid = threadIdx.x, wave = tid >> 6, lane = tid & 63;
    const int tr = lane & 15, kg = lane >> 4;

    // zero pad cols 1128..1139 (d==e reads land at c<=1128)
    for (int l = tid; l < 16 * 12; l += 256)
        sG[(l / 12) * SG2 + 1128 + (l % 12)] = 0;
    // stage x -> sXf (f32); consumed by phase B after the post-phase-A barrier
    if (tid < 192) {
        int t = tid / 12, dv = (tid % 12) * 4, tg = t0 + t;
        float4 v = make_float4(0.f, 0.f, 0.f, 0.f);
        if (tg < Tc) v = *reinterpret_cast<const float4*>(x + (((size_t)b * Tc + tg) * Nc + n) * Dc + dv);
        *reinterpret_cast<float4*>(&sXf[t * 52 + dv]) = v;
    }
    // A-frags direct from global x (no LDS round-trip, no barrier needed)
    short8 af0, af1;
    {
        int tg = t0 + tr; if (tg > Tc - 1) tg = Tc - 1;
        const float* xrow = x + (((size_t)b * Tc + tg) * Nc + n) * Dc;
        float4 a0 = *reinterpret_cast<const float4*>(xrow + kg * 8);
        float4 a1 = *reinterpret_cast<const float4*>(xrow + kg * 8 + 4);
        af0 = pack8(a0, a1);
        if (kg < 2) {   // k 32..47 real; k 48..63 multiplied by kvb's zero pad
            float4 c0v = *reinterpret_cast<const float4*>(xrow + 32 + kg * 8);
            float4 c1v = *reinterpret_cast<const float4*>(xrow + 32 + kg * 8 + 4);
            af1 = pack8(c0v, c1v);
        } else af1 = (short8){0, 0, 0, 0, 0, 0, 0, 0};
    }

    // phase A: 72 c-frags = 18 iters x 4 waves; 3-slot ring, 2-deep prefetch
    const ushort* kvbn = kvb + (size_t)bn * Cc * KVP;
    short8 R0[3], R1[3];
    #pragma unroll
    for (int s = 0; s < 2; ++s) {
        int c = (wave + s * 4) * 16 + tr;              // <= 127, in range
        const ushort* p = kvbn + (size_t)c * KVP + kg * 8;
        R0[s] = *reinterpret_cast<const short8*>(p);
        R1[s] = *reinterpret_cast<const short8*>(p + 32);
    }
    #pragma unroll
    for (int u = 0; u < 18; ++u) {
        const int cur = u % 3;
        f32x4 a = (f32x4){0.f, 0.f, 0.f, 0.f};
        a = __builtin_amdgcn_mfma_f32_16x16x32_bf16(af0, R0[cur], a, 0, 0, 0);
        a = __builtin_amdgcn_mfma_f32_16x16x32_bf16(af1, R1[cur], a, 0, 0, 0);
        if (u + 2 < 18) {
            const int nxt = (u + 2) % 3;               // free slot (consumed at u-1)
            int c = (wave + (u + 2) * 4) * 16 + tr; if (c > Cc - 1) c = Cc - 1;
            const ushort* p = kvbn + (size_t)c * KVP + kg * 8;
            R0[nxt] = *reinterpret_cast<const short8*>(p);
            R1[nxt] = *reinterpret_cast<const short8*>(p + 32);
        }
        int c = (wave + u * 4) * 16 + tr;
        if (c < Cc) {
            #pragma unroll
            for (int r = 0; r < 4; ++r) {   // D: col=tr (=c), row=kg*4+r (=t)
                float g = 0.1f - 0.2f * __builtin_amdgcn_rcpf(__expf(2.0f * a[r]) + 1.0f);
                sG[(kg * 4 + r) * SG2 + c] = f2b(g);
            }
        }
    }
    __syncthreads();

    // phase B (R6/R12 structure): thread owns 3 (t,e) pairs; x and g from LDS
    int ea[3], ta[3], tea[3];
    float dxa[3];
    #pragma unroll
    for (int p = 0; p < 3; ++p) {
        int idx = tid + p * 256;
        ta[p] = idx / 48; ea[p] = idx % 48;
        tea[p] = ea[p] * (ea[p] - 1) / 2;
        dxa[p] = 0.f;
    }
    int td = 0;
    #pragma unroll 4
    for (int d = 0; d < 48; ++d) {
        #pragma unroll
        for (int p = 0; p < 3; ++p) {
            bool gt = d > ea[p];
            int c = gt ? (td + ea[p]) : (tea[p] + d);   // d==e -> c<=1128 (zeroed pad)
            float gv = b2f(sG[ta[p] * SG2 + c]);
            float xv = sXf[ta[p] * 52 + d];
            float m = gt ? xv : -xv;
            if (d == ea[p]) m = 0.f;
            dxa[p] = fmaf(m, gv, dxa[p]);
        }
        td += d;
    }
    #pragma unroll
    for (int p = 0; p < 3; ++p) {
        int tg = t0 + ta[p];
        if (tg < Tc)
            out[(((size_t)b * Tc + tg) * Nc + n) * Dc + ea[p]] = sXf[ta[p] * 52 + ea[p]] + dxa[p];
    }
}

extern "C" void kernel_launch(void* const* d_in, const int* in_sizes, int n_in,
                              void* d_out, int out_size, void* d_ws, size_t ws_size,
                              hipStream_t stream) {
    (void)in_sizes; (void)n_in; (void)out_size; (void)ws_size;
    const float* x   = (const float*)d_in[0];
    const float* ctx = (const float*)d_in[1];
    const float* Wkv = (const float*)d_in[2];
    const float* bkv = (const float*)d_in[3];
    float* out   = (float*)d_out;
    ushort* wkvb = (ushort*)d_ws;                          // 24 KB
    ushort* kvb  = (ushort*)((char*)d_ws + 32768);         // 27.7 MB

    k0w<<<dim3(12), dim3(256), 0, stream>>>(Wkv, wkvb);
    k1_kv<<<dim3(BNc, 9), dim3(256), 0, stream>>>(ctx, wkvb, bkv, kvb);
    k2_fused<<<dim3(BNc * 8), dim3(256), 0, stream>>>(x, kvb, out);
}